// Round 1
// baseline (30.876 us; speedup 1.0000x reference)
//
#include <hip/hip_runtime.h>
#include <math.h>

#define F_DIM 28
#define C_DIM 10
#define L_DIM 28
#define H_DIM 100
#define CAT_DIM 38
#define NT 256

// LDS float offsets for the packed weight block
#define oW1   0
#define ob1   3800
#define oW2m  3900
#define ob2m  6700
#define oW2s  6728
#define ob2s  9528
#define oW3   9556
#define ob3   13356
#define oW4   13456
#define ob4   16256
#define oW5   16284
#define ob5   19084
#define oW6   19184
#define ob6   21984
#define WTOT  22012

__device__ __forceinline__ float sigmoid_f(float v) {
    return 1.0f / (1.0f + expf(-v));
}

__device__ __forceinline__ float quant_f(float z) {
    // first-occurrence argmin over |z - c|, strict < keeps earliest code on tie
    float best = 0.25f;
    float bd = fabsf(z - 0.25f);
    const float cbs[8] = {0.3536f, 0.5f, 0.7071f, 1.0f, 1.4142f, 2.0f, 2.8284f, 4.0f};
#pragma unroll
    for (int i = 0; i < 8; i++) {
        float d = fabsf(z - cbs[i]);
        if (d < bd) { bd = d; best = cbs[i]; }
    }
    return best;
}

__global__ __launch_bounds__(NT, 1) void cvae_kernel(
    const float* __restrict__ x, const float* __restrict__ y, const float* __restrict__ eps,
    const float* __restrict__ W1, const float* __restrict__ b1,
    const float* __restrict__ W2m, const float* __restrict__ b2m,
    const float* __restrict__ W2s, const float* __restrict__ b2s,
    const float* __restrict__ W3, const float* __restrict__ b3,
    const float* __restrict__ W4, const float* __restrict__ b4,
    const float* __restrict__ W5, const float* __restrict__ b5,
    const float* __restrict__ W6, const float* __restrict__ b6,
    float* __restrict__ out)
{
    const int tid = threadIdx.x;

    __shared__ float w[WTOT];
    __shared__ float epss[4 * L_DIM];
    __shared__ float cat1[CAT_DIM];   // encoder input: [0..27]=v, [28..37]=y
    __shared__ float cat2[CAT_DIM];   // decoder input: [0..27]=z, [28..37]=y
    __shared__ float h[H_DIM];
    __shared__ float t[H_DIM];
    __shared__ float mu[L_DIM];
    __shared__ float lsv[L_DIM];
    __shared__ float rec[F_DIM];

    // ---- stage all weights into LDS with coalesced float4 loads ----
    {
        const float* srcs[14] = {W1, b1, W2m, b2m, W2s, b2s, W3, b3, W4, b4, W5, b5, W6, b6};
        const int    offs[14] = {oW1, ob1, oW2m, ob2m, oW2s, ob2s, oW3, ob3, oW4, ob4, oW5, ob5, oW6, ob6};
        const int    ns[14]   = {3800, 100, 2800, 28, 2800, 28, 3800, 100, 2800, 28, 2800, 100, 2800, 28};
        for (int a = 0; a < 14; a++) {
            const float4* s = (const float4*)srcs[a];
            float4* d = (float4*)(w + offs[a]);
            const int n4 = ns[a] >> 2;
            for (int i = tid; i < n4; i += NT) d[i] = s[i];
        }
        for (int i = tid; i < (4 * L_DIM) / 4; i += NT)
            ((float4*)epss)[i] = ((const float4*)eps)[i];

        if (tid < CAT_DIM) cat1[tid] = (tid < F_DIM) ? x[tid] : y[tid - F_DIM];
        if (tid >= F_DIM && tid < CAT_DIM) cat2[tid] = y[tid - F_DIM];

        // zero rows: mu_e row 3 -> out[112..139], logstd row 3 -> out[336..363]
        if (tid < L_DIM) { out[112 + tid] = 0.0f; out[336 + tid] = 0.0f; }
    }
    __syncthreads();

    // ---- encoder chain: 4 levels ----
    for (int lev = 0; lev < 4; lev++) {
        // E1: h = relu(W1 @ cat1 + b1)
        if (tid < H_DIM) {
            const float* row = w + oW1 + tid * CAT_DIM;
            float s = w[ob1 + tid];
#pragma unroll
            for (int k = 0; k < CAT_DIM; k++) s = fmaf(row[k], cat1[k], s);
            h[tid] = fmaxf(s, 0.0f);
        }
        __syncthreads();

        // E2: mu = W2m@h + b2m (wave 0); ls = sigmoid(W2s@h + b2s) (wave 1)
        if (tid < L_DIM) {
            const float* row = w + oW2m + tid * H_DIM;
            float s = w[ob2m + tid];
#pragma unroll 4
            for (int k = 0; k < H_DIM; k++) s = fmaf(row[k], h[k], s);
            mu[tid] = s;
        } else if (tid >= 64 && tid < 64 + L_DIM) {
            const int l = tid - 64;
            const float* row = w + oW2s + l * H_DIM;
            float s = w[ob2s + l];
#pragma unroll 4
            for (int k = 0; k < H_DIM; k++) s = fmaf(row[k], h[k], s);
            lsv[l] = sigmoid_f(s);
        }
        __syncthreads();

        // E3: z = mu + eps*ls ; d = quant(z) -> next cat1; write mu/ls outputs
        if (tid < L_DIM) {
            const float m = mu[tid];
            const float l = lsv[tid];
            const float z = m + epss[lev * L_DIM + tid] * l;
            cat1[tid] = quant_f(z);
            if (lev < 3) {
                out[28 + lev * 28 + tid]  = m;   // mu_e rows 0..2
                out[252 + lev * 28 + tid] = l;   // logstd rows 0..2
            }
        }
        __syncthreads();
    }

    // d4 now in cat1[0..27]; copy to decoder input slot
    if (tid < L_DIM) cat2[tid] = cat1[tid];
    __syncthreads();

    // ---- decoder chain: s3 = 3,2,1,0 ----
    for (int s3 = 3; s3 >= 0; s3--) {
        // D1: h = relu(W3 @ cat2 + b3)
        if (tid < H_DIM) {
            const float* row = w + oW3 + tid * CAT_DIM;
            float s = w[ob3 + tid];
#pragma unroll
            for (int k = 0; k < CAT_DIM; k++) s = fmaf(row[k], cat2[k], s);
            h[tid] = fmaxf(s, 0.0f);
        }
        __syncthreads();

        // D2: rec = sigmoid(W4 @ h + b4)
        if (tid < F_DIM) {
            const float* row = w + oW4 + tid * H_DIM;
            float s = w[ob4 + tid];
#pragma unroll 4
            for (int k = 0; k < H_DIM; k++) s = fmaf(row[k], h[k], s);
            const float r = sigmoid_f(s);
            rec[tid] = r;
            if (s3 == 0) out[tid] = r;   // recon0
        }
        __syncthreads();

        // D3: t = W5 @ rec + b5 (waves 0/1); next cat2 = quant(rec) (wave 2)
        if (tid < H_DIM) {
            const float* row = w + oW5 + tid * F_DIM;
            float s = w[ob5 + tid];
#pragma unroll
            for (int k = 0; k < F_DIM; k++) s = fmaf(row[k], rec[k], s);
            t[tid] = s;
        } else if (tid >= 128 && tid < 128 + F_DIM) {
            const int l = tid - 128;
            cat2[l] = quant_f(rec[l]);
        }
        __syncthreads();

        // D4: mud = W6 @ t + b6 -> mu_d row s3
        if (tid < L_DIM) {
            const float* row = w + oW6 + tid * H_DIM;
            float s = w[ob6 + tid];
#pragma unroll 4
            for (int k = 0; k < H_DIM; k++) s = fmaf(row[k], t[k], s);
            out[140 + s3 * 28 + tid] = s;
        }
        __syncthreads();
    }
}

extern "C" void kernel_launch(void* const* d_in, const int* in_sizes, int n_in,
                              void* d_out, int out_size, void* d_ws, size_t ws_size,
                              hipStream_t stream) {
    const float* x   = (const float*)d_in[0];
    const float* y   = (const float*)d_in[1];
    const float* eps = (const float*)d_in[2];
    const float* W1  = (const float*)d_in[3];
    const float* b1  = (const float*)d_in[4];
    const float* W2m = (const float*)d_in[5];
    const float* b2m = (const float*)d_in[6];
    const float* W2s = (const float*)d_in[7];
    const float* b2s = (const float*)d_in[8];
    const float* W3  = (const float*)d_in[9];
    const float* b3  = (const float*)d_in[10];
    const float* W4  = (const float*)d_in[11];
    const float* b4  = (const float*)d_in[12];
    const float* W5  = (const float*)d_in[13];
    const float* b5  = (const float*)d_in[14];
    const float* W6  = (const float*)d_in[15];
    const float* b6  = (const float*)d_in[16];
    float* out = (float*)d_out;

    cvae_kernel<<<1, NT, 0, stream>>>(x, y, eps, W1, b1, W2m, b2m, W2s, b2s,
                                      W3, b3, W4, b4, W5, b5, W6, b6, out);
}

// Round 3
// 24.566 us; speedup vs baseline: 1.2568x; 1.2568x over previous
//
#include <hip/hip_runtime.h>
#include <math.h>

#define NT 256

// LDS float offsets (all float4-aligned); W1/W3 rows padded 38->44 floats
#define oW1p 0
#define ob1  4400
#define oW2m 4500
#define ob2m 7300
#define oW2s 7328
#define ob2s 10128
#define oW4  10156
#define ob4  12956
#define oW5  12984
#define ob5  15784
#define oW6  15884
#define ob6  18684
#define oW3p 18712
#define ob3  23112
#define WTOT 23212

__device__ __forceinline__ float sigmoid_f(float v) {
    return 1.0f / (1.0f + expf(-v));
}

__device__ __forceinline__ float quant_f(float z) {
    // first-occurrence argmin over |z - c| (strict < keeps earliest code on tie)
    float best = 0.25f;
    float bd = fabsf(z - 0.25f);
    const float cbs[8] = {0.3536f, 0.5f, 0.7071f, 1.0f, 1.4142f, 2.0f, 2.8284f, 4.0f};
#pragma unroll
    for (int i = 0; i < 8; i++) {
        float d = fabsf(z - cbs[i]);
        if (d < bd) { bd = d; best = cbs[i]; }
    }
    return best;
}

// dot product via float4 LDS reads, 4 independent accumulators
template<int N4>
__device__ __forceinline__ float dotf4(const float* __restrict__ row, const float* __restrict__ vec) {
    const float4* r = (const float4*)row;
    const float4* v = (const float4*)vec;
    float a0 = 0.0f, a1 = 0.0f, a2 = 0.0f, a3 = 0.0f;
#pragma unroll
    for (int i = 0; i < N4; i++) {
        float4 rv = r[i];
        float4 vv = v[i];
        a0 = fmaf(rv.x, vv.x, a0);
        a1 = fmaf(rv.y, vv.y, a1);
        a2 = fmaf(rv.z, vv.z, a2);
        a3 = fmaf(rv.w, vv.w, a3);
    }
    return (a0 + a1) + (a2 + a3);
}

__global__ __launch_bounds__(NT, 1) void cvae_kernel(
    const float* __restrict__ x, const float* __restrict__ y, const float* __restrict__ eps,
    const float* __restrict__ W1, const float* __restrict__ b1,
    const float* __restrict__ W2m, const float* __restrict__ b2m,
    const float* __restrict__ W2s, const float* __restrict__ b2s,
    const float* __restrict__ W3, const float* __restrict__ b3,
    const float* __restrict__ W4, const float* __restrict__ b4,
    const float* __restrict__ W5, const float* __restrict__ b5,
    const float* __restrict__ W6, const float* __restrict__ b6,
    float* __restrict__ out)
{
    const int tid = threadIdx.x;

    __shared__ __align__(16) float w[WTOT];
    __shared__ __align__(16) float h[100];
    __shared__ __align__(16) float t[100];
    __shared__ __align__(16) float rec[28];
    __shared__ __align__(16) float catv[44];   // [0..27]=z/x, [28..37]=y, [38..43]=0
    __shared__ __align__(16) float epss[112];

    // ---- stage weights into LDS ----
#define STG4(SRC, OFF, N) { const float4* s_ = (const float4*)(SRC); float4* d_ = (float4*)(w + (OFF)); \
                            for (int i = tid; i < (N)/4; i += NT) d_[i] = s_[i]; }
    STG4(b1,  ob1,  100);
    STG4(W2m, oW2m, 2800);  STG4(b2m, ob2m, 28);
    STG4(W2s, oW2s, 2800);  STG4(b2s, ob2s, 28);
    STG4(W4,  oW4,  2800);  STG4(b4,  ob4,  28);
    STG4(W5,  oW5,  2800);  STG4(b5,  ob5,  100);
    STG4(W6,  oW6,  2800);  STG4(b6,  ob6,  28);
    STG4(b3,  ob3,  100);
#undef STG4
    for (int i = tid; i < 28; i += NT)
        ((float4*)epss)[i] = ((const float4*)eps)[i];

    // W1 / W3: 100 rows x 38 floats -> padded stride 44, staged as float2
    for (int i = tid; i < 1900; i += NT) {
        int r = i / 19, c = i - r * 19;
        ((float2*)(w + oW1p))[r * 22 + c] = ((const float2*)W1)[i];
        ((float2*)(w + oW3p))[r * 22 + c] = ((const float2*)W3)[i];
    }
    if (tid < 100) {
#pragma unroll
        for (int c = 38; c < 44; c++) {
            w[oW1p + tid * 44 + c] = 0.0f;
            w[oW3p + tid * 44 + c] = 0.0f;
        }
    }
    if (tid < 28) catv[tid] = x[tid];
    if (tid < 16) catv[28 + tid] = (tid < 10) ? y[tid] : 0.0f;
    // zero rows: mu_e row 3 (out[112..139]), logstd row 3 (out[336..363])
    if (tid < 28) { out[112 + tid] = 0.0f; out[336 + tid] = 0.0f; }
    __syncthreads();

    // ---- encoder: 4 levels, 2 stages each ----
    for (int lev = 0; lev < 4; lev++) {
        // E1: h = relu(W1 @ cat + b1), lanes 0..99
        if (tid < 100)
            h[tid] = fmaxf(dotf4<11>(w + oW1p + tid * 44, catv) + w[ob1 + tid], 0.0f);
        __syncthreads();

        // E2+E3 fused on wave 0: lanes 0-27 mu, lanes 32-59 log_std; shfl to combine
        if (tid < 64) {
            int r = tid & 31; if (r > 27) r = 27;
            const bool isMu = tid < 32;
            const float* row = w + (isMu ? oW2m : oW2s) + r * 100;
            float s = dotf4<25>(row, h) + w[(isMu ? ob2m : ob2s) + r];
            float val = isMu ? s : sigmoid_f(s);
            float oth = __shfl(val, (tid & 31) + 32);   // lane i<28 gets ls_i
            if (tid < 28) {
                float zq = fmaf(epss[lev * 28 + tid], oth, val);  // mu + eps*ls
                catv[tid] = quant_f(zq);
                if (lev < 3) out[28 + lev * 28 + tid] = val;      // mu_e row
            } else if (tid >= 32 && tid < 60 && lev < 3) {
                out[252 + lev * 28 + (tid - 32)] = val;            // logstd row
            }
        }
        __syncthreads();
    }

    // ---- decoder: initial fc3, then 4 steps of 3 stages ----
    if (tid < 100)
        h[tid] = fmaxf(dotf4<11>(w + oW3p + tid * 44, catv) + w[ob3 + tid], 0.0f);
    __syncthreads();

    for (int s3 = 3; s3 >= 0; s3--) {
        // D2 + quant fused: lanes 0-27
        if (tid < 28) {
            float s = dotf4<25>(w + oW4 + tid * 100, h) + w[ob4 + tid];
            float rv = sigmoid_f(s);
            rec[tid] = rv;
            catv[tid] = quant_f(rv);
            if (s3 == 0) out[tid] = rv;          // recon0
        }
        __syncthreads();

        // D3: t = W5 @ rec + b5, lanes 0..99
        if (tid < 100)
            t[tid] = dotf4<7>(w + oW5 + tid * 28, rec) + w[ob5 + tid];
        __syncthreads();

        // D4 (mu_d row) on lanes 0-27, in parallel with NEXT step's fc3 on lanes 64-163
        if (tid < 28) {
            out[140 + s3 * 28 + tid] = dotf4<25>(w + oW6 + tid * 100, t) + w[ob6 + tid];
        } else if (s3 > 0 && tid >= 64 && tid < 164) {
            int j = tid - 64;
            h[j] = fmaxf(dotf4<11>(w + oW3p + j * 44, catv) + w[ob3 + j], 0.0f);
        }
        __syncthreads();
    }
}

extern "C" void kernel_launch(void* const* d_in, const int* in_sizes, int n_in,
                              void* d_out, int out_size, void* d_ws, size_t ws_size,
                              hipStream_t stream) {
    const float* x   = (const float*)d_in[0];
    const float* y   = (const float*)d_in[1];
    const float* eps = (const float*)d_in[2];
    const float* W1  = (const float*)d_in[3];
    const float* b1  = (const float*)d_in[4];
    const float* W2m = (const float*)d_in[5];
    const float* b2m = (const float*)d_in[6];
    const float* W2s = (const float*)d_in[7];
    const float* b2s = (const float*)d_in[8];
    const float* W3  = (const float*)d_in[9];
    const float* b3  = (const float*)d_in[10];
    const float* W4  = (const float*)d_in[11];
    const float* b4  = (const float*)d_in[12];
    const float* W5  = (const float*)d_in[13];
    const float* b5  = (const float*)d_in[14];
    const float* W6  = (const float*)d_in[15];
    const float* b6  = (const float*)d_in[16];
    float* out = (float*)d_out;

    cvae_kernel<<<1, NT, 0, stream>>>(x, y, eps, W1, b1, W2m, b2m, W2s, b2s,
                                      W3, b3, W4, b4, W5, b5, W6, b6, out);
}

// Round 4
// 16.295 us; speedup vs baseline: 1.8948x; 1.5076x over previous
//
#include <hip/hip_runtime.h>
#include <math.h>

#define NT 256

__device__ __forceinline__ float sigmoid_f(float v) {
    return 1.0f / (1.0f + expf(-v));
}

__device__ __forceinline__ float quant_f(float z) {
    // first-occurrence argmin over |z - c| (strict < keeps earliest code on tie)
    float best = 0.25f;
    float bd = fabsf(z - 0.25f);
    const float cbs[8] = {0.3536f, 0.5f, 0.7071f, 1.0f, 1.4142f, 2.0f, 2.8284f, 4.0f};
#pragma unroll
    for (int i = 0; i < 8; i++) {
        float d = fabsf(z - cbs[i]);
        if (d < bd) { bd = d; best = cbs[i]; }
    }
    return best;
}

// dot of weight-registers (static-indexed) against an LDS vector read as float4
template<int N4>
__device__ __forceinline__ float dot_rl(const float* wr, const float* v) {
    const float4* v4 = (const float4*)v;
    float a0 = 0.f, a1 = 0.f, a2 = 0.f, a3 = 0.f;
#pragma unroll
    for (int i = 0; i < N4; i++) {
        float4 vv = v4[i];
        a0 = fmaf(wr[4*i+0], vv.x, a0);
        a1 = fmaf(wr[4*i+1], vv.y, a1);
        a2 = fmaf(wr[4*i+2], vv.z, a2);
        a3 = fmaf(wr[4*i+3], vv.w, a3);
    }
    return (a0 + a1) + (a2 + a3);
}

__device__ __forceinline__ int sliceStart(int g) {  // 100-wide operand slices 28/24/24/24
    return g == 0 ? 0 : (g == 1 ? 28 : (g == 2 ? 52 : 76));
}

__global__ __launch_bounds__(NT, 1) void cvae_kernel(
    const float* __restrict__ x, const float* __restrict__ y, const float* __restrict__ eps,
    const float* __restrict__ W1, const float* __restrict__ b1,
    const float* __restrict__ W2m, const float* __restrict__ b2m,
    const float* __restrict__ W2s, const float* __restrict__ b2s,
    const float* __restrict__ W3, const float* __restrict__ b3,
    const float* __restrict__ W4, const float* __restrict__ b4,
    const float* __restrict__ W5, const float* __restrict__ b5,
    const float* __restrict__ W6, const float* __restrict__ b6,
    float* __restrict__ out)
{
    const int tid = threadIdx.x;

    // small LDS activation buffers; slice bases are all 16B-aligned
    __shared__ __align__(16) float cat0[20];      // enc input cols 0..19
    __shared__ __align__(16) float cat1[20];      // enc input cols 20..37 (+2 zero)
    __shared__ __align__(16) float cat2v[40];     // dec input [z(28)|y(10)|0,0]
    __shared__ __align__(16) float h_lds[4][28];  // fc1/fc3 output, slices 28/24/24/24 (+pad zeros)
    __shared__ __align__(16) float t_lds[4][28];  // fc5 output, same layout
    __shared__ __align__(16) float rec_lds[2][16];// rec slices 14/14 (+2 zero each)

    // ---- lane roles (fixed per thread) ----
    const int r1 = tid >> 1, p1 = tid & 1;        // E1 (W1) + B (W5): 2 lanes/row, tid<200
    const int r2 = tid >> 3, c2 = tid & 7;        // E2E3: 8 lanes/row, tid<224
    const int g2 = c2 & 3;
    const int r4 = tid >> 2, g4 = tid & 3;        // A (W4) + C-mud (W6): 4 lanes/row, tid<112
    const int r3 = tid - 128;                     // fc3 (W3): 1 lane/row, 128<=tid<228

    // destination offsets into h_lds/t_lds (flat) for the 100-entry outputs
    const int hg  = (r1 < 28) ? 0 : ((r1 < 52) ? 1 : ((r1 < 76) ? 2 : 3));
    const int ho  = hg * 28 + (r1 - sliceStart(hg));
    const int h3g = (r3 < 28) ? 0 : ((r3 < 52) ? 1 : ((r3 < 76) ? 2 : 3));
    const int h3o = h3g * 28 + (r3 - sliceStart(h3g));

    // ---- weight/bias/eps loads into registers (once; L2-hot on replays) ----
    float w1s[20]; float b1r = 0.f;
    if (tid < 200) {
        const float2* s2 = (const float2*)(W1 + r1 * 38 + p1 * 20);  // even offset -> 8B aligned
        if (p1 == 0) {
#pragma unroll
            for (int i = 0; i < 10; i++) { float2 v = s2[i]; w1s[2*i] = v.x; w1s[2*i+1] = v.y; }
            b1r = b1[r1];
        } else {
#pragma unroll
            for (int i = 0; i < 9; i++) { float2 v = s2[i]; w1s[2*i] = v.x; w1s[2*i+1] = v.y; }
            w1s[18] = 0.f; w1s[19] = 0.f;
        }
    }

    float w2s[28]; float b2r = 0.f; float er[4] = {0.f, 0.f, 0.f, 0.f};
    if (tid < 224) {
        const float* mat = (c2 < 4) ? W2m : W2s;
        const float4* s4 = (const float4*)(mat + r2 * 100 + sliceStart(g2));  // starts 0/28/52/76: 16B aligned
        if (g2 == 0) {
#pragma unroll
            for (int i = 0; i < 7; i++) { float4 v = s4[i]; w2s[4*i] = v.x; w2s[4*i+1] = v.y; w2s[4*i+2] = v.z; w2s[4*i+3] = v.w; }
        } else {
#pragma unroll
            for (int i = 0; i < 6; i++) { float4 v = s4[i]; w2s[4*i] = v.x; w2s[4*i+1] = v.y; w2s[4*i+2] = v.z; w2s[4*i+3] = v.w; }
            w2s[24] = 0.f; w2s[25] = 0.f; w2s[26] = 0.f; w2s[27] = 0.f;
        }
        if (c2 == 0) {
            b2r = b2m[r2];
            er[0] = eps[r2]; er[1] = eps[28 + r2]; er[2] = eps[56 + r2]; er[3] = eps[84 + r2];
        }
        if (c2 == 4) b2r = b2s[r2];
    }

    float w4s[28], w6s[28]; float b4r = 0.f, b6r = 0.f;
    if (tid < 112) {
        const float4* s4 = (const float4*)(W4 + r4 * 100 + sliceStart(g4));
        const float4* s6 = (const float4*)(W6 + r4 * 100 + sliceStart(g4));
        if (g4 == 0) {
#pragma unroll
            for (int i = 0; i < 7; i++) { float4 v = s4[i]; w4s[4*i] = v.x; w4s[4*i+1] = v.y; w4s[4*i+2] = v.z; w4s[4*i+3] = v.w; }
#pragma unroll
            for (int i = 0; i < 7; i++) { float4 v = s6[i]; w6s[4*i] = v.x; w6s[4*i+1] = v.y; w6s[4*i+2] = v.z; w6s[4*i+3] = v.w; }
            b4r = b4[r4]; b6r = b6[r4];
        } else {
#pragma unroll
            for (int i = 0; i < 6; i++) { float4 v = s4[i]; w4s[4*i] = v.x; w4s[4*i+1] = v.y; w4s[4*i+2] = v.z; w4s[4*i+3] = v.w; }
#pragma unroll
            for (int i = 0; i < 6; i++) { float4 v = s6[i]; w6s[4*i] = v.x; w6s[4*i+1] = v.y; w6s[4*i+2] = v.z; w6s[4*i+3] = v.w; }
            w4s[24] = 0.f; w4s[25] = 0.f; w4s[26] = 0.f; w4s[27] = 0.f;
            w6s[24] = 0.f; w6s[25] = 0.f; w6s[26] = 0.f; w6s[27] = 0.f;
        }
    }

    float w5s[16]; float b5r = 0.f;
    if (tid < 200) {
        const float2* s2 = (const float2*)(W5 + r1 * 28 + p1 * 14);  // even offset
#pragma unroll
        for (int i = 0; i < 7; i++) { float2 v = s2[i]; w5s[2*i] = v.x; w5s[2*i+1] = v.y; }
        w5s[14] = 0.f; w5s[15] = 0.f;
        if (p1 == 0) b5r = b5[r1];
    }

    float w3s[40]; float b3r = 0.f;
    if (tid >= 128 && tid < 228) {
        const float2* s2 = (const float2*)(W3 + r3 * 38);  // even offset
#pragma unroll
        for (int i = 0; i < 19; i++) { float2 v = s2[i]; w3s[2*i] = v.x; w3s[2*i+1] = v.y; }
        w3s[38] = 0.f; w3s[39] = 0.f;
        b3r = b3[r3];
    }

    // ---- LDS init (pads zeroed once; y written once; x loaded) ----
    if (tid < 28) {
        float xv = x[tid];
        if (tid < 20) cat0[tid] = xv; else cat1[tid - 20] = xv;
        out[112 + tid] = 0.f;   // mu_e row 3
        out[336 + tid] = 0.f;   // logstd row 3
    }
    if (tid < 10) { float yv = y[tid]; cat1[8 + tid] = yv; cat2v[28 + tid] = yv; }
    if (tid == 0) { cat1[18] = 0.f; cat1[19] = 0.f; cat2v[38] = 0.f; cat2v[39] = 0.f; }
    if (tid >= 1 && tid < 4) {
#pragma unroll
        for (int j = 24; j < 28; j++) { h_lds[tid][j] = 0.f; t_lds[tid][j] = 0.f; }
    }
    if (tid < 2) { rec_lds[tid][14] = 0.f; rec_lds[tid][15] = 0.f; }
    __syncthreads();

    // ---- encoder: 4 levels x 2 stages ----
#pragma unroll
    for (int lev = 0; lev < 4; lev++) {
        // E1: h = relu(W1 @ cat + b1), 2 lanes/row over all 4 waves
        if (tid < 200) {
            float s = dot_rl<5>(w1s, p1 ? cat1 : cat0);
            s += __shfl_xor(s, 1);
            if (p1 == 0) ((float*)h_lds)[ho] = fmaxf(s + b1r, 0.f);
        }
        __syncthreads();

        // E2+E3 fused: 8 lanes/row (4 mu + 4 ls), shfl-reduce, quant inline
        if (tid < 224) {
            float s = dot_rl<7>(w2s, h_lds[g2]);
            s += __shfl_xor(s, 1);
            s += __shfl_xor(s, 2);
            float fin = 0.f;
            if (c2 == 0)      fin = s + b2r;               // mu[r2]
            else if (c2 == 4) fin = sigmoid_f(s + b2r);    // ls[r2]
            float oth = __shfl_xor(fin, 4);                // c0 gets ls, c4 gets mu
            if (c2 == 0) {
                float z = quant_f(fmaf(er[lev], oth, fin));
                if (r2 < 20) cat0[r2] = z; else cat1[r2 - 20] = z;   // next enc input
                cat2v[r2] = z;                                        // dec input (last level wins)
                if (lev < 3) out[28 + lev * 28 + r2] = fin;           // mu_e row
            } else if (c2 == 4 && lev < 3) {
                out[252 + lev * 28 + r2] = fin;                       // logstd row
            }
        }
        __syncthreads();
    }

    // ---- decoder init: h = relu(W3 @ [d4|y] + b3), 1 lane/row on waves 2-3 ----
    if (tid >= 128 && tid < 228) {
        float s = dot_rl<10>(w3s, cat2v);
        ((float*)h_lds)[h3o] = fmaxf(s + b3r, 0.f);
    }
    __syncthreads();

    // ---- decoder: 4 steps x 3 stages ----
    for (int s3 = 3; s3 >= 0; s3--) {
        // A: rec = sigmoid(W4 @ h + b4); quant(rec) -> cat2v; (waves 0-1)
        if (tid < 112) {
            float s = dot_rl<7>(w4s, h_lds[g4]);
            s += __shfl_xor(s, 1);
            s += __shfl_xor(s, 2);
            if (g4 == 0) {
                float rv = sigmoid_f(s + b4r);
                if (r4 < 14) rec_lds[0][r4] = rv; else rec_lds[1][r4 - 14] = rv;
                cat2v[r4] = quant_f(rv);
                if (s3 == 0) out[r4] = rv;      // recon0
            }
        }
        __syncthreads();

        // B: t = W5 @ rec + b5, 2 lanes/row over all 4 waves
        if (tid < 200) {
            float s = dot_rl<4>(w5s, p1 ? rec_lds[1] : rec_lds[0]);
            s += __shfl_xor(s, 1);
            if (p1 == 0) ((float*)t_lds)[ho] = s + b5r;
        }
        __syncthreads();

        // C: mud = W6 @ t + b6 (waves 0-1)  ||  next h = relu(W3 @ cat2 + b3) (waves 2-3)
        if (tid < 112) {
            float s = dot_rl<7>(w6s, t_lds[g4]);
            s += __shfl_xor(s, 1);
            s += __shfl_xor(s, 2);
            if (g4 == 0) out[140 + s3 * 28 + r4] = s + b6r;   // mu_d row s3
        } else if (s3 > 0 && tid >= 128 && tid < 228) {
            float s = dot_rl<10>(w3s, cat2v);
            ((float*)h_lds)[h3o] = fmaxf(s + b3r, 0.f);
        }
        __syncthreads();
    }
}

extern "C" void kernel_launch(void* const* d_in, const int* in_sizes, int n_in,
                              void* d_out, int out_size, void* d_ws, size_t ws_size,
                              hipStream_t stream) {
    const float* x   = (const float*)d_in[0];
    const float* y   = (const float*)d_in[1];
    const float* eps = (const float*)d_in[2];
    const float* W1  = (const float*)d_in[3];
    const float* b1  = (const float*)d_in[4];
    const float* W2m = (const float*)d_in[5];
    const float* b2m = (const float*)d_in[6];
    const float* W2s = (const float*)d_in[7];
    const float* b2s = (const float*)d_in[8];
    const float* W3  = (const float*)d_in[9];
    const float* b3  = (const float*)d_in[10];
    const float* W4  = (const float*)d_in[11];
    const float* b4  = (const float*)d_in[12];
    const float* W5  = (const float*)d_in[13];
    const float* b5  = (const float*)d_in[14];
    const float* W6  = (const float*)d_in[15];
    const float* b6  = (const float*)d_in[16];
    float* out = (float*)d_out;

    cvae_kernel<<<1, NT, 0, stream>>>(x, y, eps, W1, b1, W2m, b2m, W2s, b2s,
                                      W3, b3, W4, b4, W5, b5, W6, b6, out);
}